// Round 5
// baseline (305.423 us; speedup 1.0000x reference)
//
#include <hip/hip_runtime.h>
#include <math.h>

#define NN 20480
#define NE 327680
#define NBATCH 16

typedef float v2f __attribute__((ext_vector_type(2)));

#if __has_builtin(__builtin_elementwise_max)
#define VMAX0(a) __builtin_elementwise_max((a), (v2f){0.f, 0.f})
#else
static __device__ __forceinline__ v2f VMAX0(v2f a) {
  v2f r; r.x = fmaxf(a.x, 0.f); r.y = fmaxf(a.y, 0.f); return r;
}
#endif

// ---------------- counting-sort: histogram ---------------------------------
__global__ void hist_kernel(const int* __restrict__ dst, int* __restrict__ cnt) {
  int e = blockIdx.x * blockDim.x + threadIdx.x;
  if (e < NE) atomicAdd(&cnt[dst[e]], 1);
}

// ------- exclusive scan over NN counts (1 block); writes off AND cur --------
__global__ __launch_bounds__(1024) void scan_kernel(const int* __restrict__ cnt,
                                                    int* __restrict__ off,
                                                    int* __restrict__ cur) {
  __shared__ int part[1024];
  int tid = threadIdx.x;
  const int PT = NN / 1024;              // 20 per thread
  int loc[PT];
  int run = 0;
  int base = tid * PT;
#pragma unroll
  for (int k = 0; k < PT; k++) { loc[k] = run; run += cnt[base + k]; }
  part[tid] = run;
  __syncthreads();
  for (int d = 1; d < 1024; d <<= 1) {
    int t = (tid >= d) ? part[tid - d] : 0;
    __syncthreads();
    part[tid] += t;
    __syncthreads();
  }
  int pre = (tid == 0) ? 0 : part[tid - 1];
#pragma unroll
  for (int k = 0; k < PT; k++) {
    off[base + k] = pre + loc[k];
    cur[base + k] = pre + loc[k];
  }
  if (tid == 1023) off[NN] = pre + run;  // == NE
}

__global__ void scatter_kernel(const int* __restrict__ src, const int* __restrict__ dst,
                               const int* __restrict__ etype, const float* __restrict__ eattr,
                               int* __restrict__ cur, float4* __restrict__ es) {
  int e = blockIdx.x * blockDim.x + threadIdx.x;
  if (e >= NE) return;
  int d = dst[e];
  int pos = atomicAdd(&cur[d], 1);
  es[pos] = make_float4(__int_as_float(src[e]), __int_as_float(etype[e]),
                        eattr[2 * e], eattr[2 * e + 1]);
}

// ---------------- emb transpose: [t][i][o] -> [t][o][i] ---------------------
// Makes each lane's 8 i-values contiguous -> 2x dwordx4 per edge instead of
// 8 strided scalar loads. 18432 threads total.
__global__ __launch_bounds__(256) void transpose_kernel(
    const float* __restrict__ e1, const float* __restrict__ e2,
    const float* __restrict__ e3, const float* __restrict__ e4,
    float* __restrict__ t1, float* __restrict__ t2,
    float* __restrict__ t3, float* __restrict__ t4) {
  int idx = blockIdx.x * 256 + threadIdx.x;      // 0 .. 18431
  if (idx < 36 * 128) {
    int t = idx >> 7, r = idx & 127, o = r >> 4, i = r & 15;
    t1[idx] = e1[(t << 7) + i * 8 + o];
  }
  if (idx < 36 * 64) {
    int t = idx >> 6, r = idx & 63, o = r >> 3, i = r & 7;
    t2[idx] = e2[(t << 6) + i * 8 + o];
    t3[idx] = e3[(t << 6) + i * 8 + o];
  }
  {
    int t = idx >> 9, r = idx & 511, o = r >> 3, i = r & 7;
    t4[idx] = e4[(t << 9) + i * 64 + o];
  }
}

// ---------------- fused layer 1 (cin=16, cout=8) ----------------------------
// 1 node/wave. lane = (esub[2b]<<4)|(ihalf<<3)|o. 4 edges x 2 i-halves x 8 out
// per iteration; 2-stage software pipeline on (es record, h row).
__global__ __launch_bounds__(256) void layer_small16(
    const int* __restrict__ off, const float4* __restrict__ es,
    const float* __restrict__ h_in, const float* __restrict__ embT,
    const float* __restrict__ wh, const float* __restrict__ bh,
    const float* __restrict__ wg, const float* __restrict__ bg,
    const float* __restrict__ root, const float* __restrict__ bias,
    float* __restrict__ h_out) {
  constexpr int D = 128;
  int lane = threadIdx.x & 63;
  int o = lane & 7;
  int ihalf = (lane >> 3) & 1;
  int esub = lane >> 4;                  // 0..3
  int ibase = ihalf * 8;
  v2f rwh0[4], rwh1[4], rbh[4], rwg0[4], rwg1[4], rbg[4], rroot[4];
#pragma unroll
  for (int p = 0; p < 4; p++) {
    int a = (ibase + 2 * p) * 8 + o, b = (ibase + 2 * p + 1) * 8 + o;
    rwh0[p] = (v2f){wh[a], wh[b]};
    rwh1[p] = (v2f){wh[D + a], wh[D + b]};
    rbh[p]  = (v2f){bh[a], bh[b]};
    rwg0[p] = (v2f){wg[a], wg[b]};
    rwg1[p] = (v2f){wg[D + a], wg[D + b]};
    rbg[p]  = (v2f){bg[a], bg[b]};
    rroot[p] = (v2f){root[a], root[b]};
  }
  float rbias = bias[o];
  int n = __builtin_amdgcn_readfirstlane((int)(blockIdx.x * 4) + (int)(threadIdx.x >> 6));
  int beg = off[n], end = off[n + 1];
  int nIter = (end - beg + 3) >> 2;
  float acc = 0.f;
  int j = beg + esub;
  bool val0 = j < end;
  float4 rec0 = val0 ? es[j] : make_float4(0.f, 0.f, 0.f, 0.f);
  int s0 = __float_as_int(rec0.x);
  const float4* hp0 = (const float4*)(h_in + s0 * 16 + ibase);
  float4 hA0 = hp0[0], hB0 = hp0[1];
  for (int it = 0; it < nIter; ++it) {
    int j1 = j + 4;
    bool val1 = j1 < end;
    float4 rec1 = val1 ? es[j1] : make_float4(0.f, 0.f, 0.f, 0.f);
    int s1 = __float_as_int(rec1.x);
    const float4* hp1 = (const float4*)(h_in + s1 * 16 + ibase);
    float4 hA1 = hp1[0], hB1 = hp1[1];
    // compute current stage
    int t0 = __float_as_int(rec0.y);
    const float4* sp = (const float4*)(embT + t0 * 128 + o * 16 + ibase);
    float4 sv0 = sp[0], sv1 = sp[1];
    v2f stv[4] = {(v2f){sv0.x, sv0.y}, (v2f){sv0.z, sv0.w},
                  (v2f){sv1.x, sv1.y}, (v2f){sv1.z, sv1.w}};
    v2f hv[4] = {(v2f){hA0.x, hA0.y}, (v2f){hA0.z, hA0.w},
                 (v2f){hB0.x, hB0.y}, (v2f){hB0.z, hB0.w}};
    v2f ef0 = (v2f){rec0.z, rec0.z}, ef1 = (v2f){rec0.w, rec0.w};
    v2f msg = {0.f, 0.f};
#pragma unroll
    for (int p = 0; p < 4; p++) {
      v2f hval = ef0 * rwh0[p] + ef1 * rwh1[p] + rbh[p];
      v2f gval = ef0 * rwg0[p] + ef1 * rwg1[p] + rbg[p];
      msg += hv[p] * VMAX0(stv[p] * hval + gval);
    }
    acc += val0 ? (msg.x + msg.y) : 0.f;
    rec0 = rec1; hA0 = hA1; hB0 = hB1; val0 = val1; j = j1;
  }
  // xor8 combines i-halves; xor16/32 combine edge groups
  acc += __shfl_xor(acc, 8);
  acc += __shfl_xor(acc, 16);
  acc += __shfl_xor(acc, 32);
  const float* hn = h_in + n * 16 + ibase;
  v2f rtv = {0.f, 0.f};
#pragma unroll
  for (int p = 0; p < 4; p++)
    rtv += (v2f){hn[2 * p], hn[2 * p + 1]} * rroot[p];
  float rt = rtv.x + rtv.y;
  rt += __shfl_xor(rt, 8);
  float deg = (float)(end - beg);
  float val = fmaxf(rbias + rt + acc / fmaxf(deg, 1.f), 0.f);
  if (lane < 8) h_out[n * 8 + o] = val;
}

// ---------------- fused layer, cin=8 cout=8 (L2,L3) -------------------------
// 1 node/wave. lane=(esub<<3)|o: 8 edges x 8 outputs per iteration; 2-stage
// software pipeline on (es record, h row). embT from global (9KB, L1-hot).
__global__ __launch_bounds__(256) void layer_small8(
    const int* __restrict__ off, const float4* __restrict__ es,
    const float* __restrict__ h_in, const float* __restrict__ embT,
    const float* __restrict__ wh, const float* __restrict__ bh,
    const float* __restrict__ wg, const float* __restrict__ bg,
    const float* __restrict__ root, const float* __restrict__ bias,
    float* __restrict__ h_out) {
  int lane = threadIdx.x & 63;
  int o = lane & 7, esub = lane >> 3;
  v2f rwh0[4], rwh1[4], rbh[4], rwg0[4], rwg1[4], rbg[4], rroot[4];
#pragma unroll
  for (int p = 0; p < 4; p++) {
    int a = (2 * p) * 8 + o, b = (2 * p + 1) * 8 + o;
    rwh0[p] = (v2f){wh[a], wh[b]};
    rwh1[p] = (v2f){wh[64 + a], wh[64 + b]};
    rbh[p]  = (v2f){bh[a], bh[b]};
    rwg0[p] = (v2f){wg[a], wg[b]};
    rwg1[p] = (v2f){wg[64 + a], wg[64 + b]};
    rbg[p]  = (v2f){bg[a], bg[b]};
    rroot[p] = (v2f){root[a], root[b]};
  }
  float rbias = bias[o];
  int n = __builtin_amdgcn_readfirstlane((int)(blockIdx.x * 4) + (int)(threadIdx.x >> 6));
  int beg = off[n], end = off[n + 1];
  int nIter = (end - beg + 7) >> 3;
  float acc = 0.f;
  int j = beg + esub;
  bool val0 = j < end;
  float4 rec0 = val0 ? es[j] : make_float4(0.f, 0.f, 0.f, 0.f);
  int s0 = __float_as_int(rec0.x);
  const float4* hp0 = (const float4*)(h_in + s0 * 8);
  float4 hA0 = hp0[0], hB0 = hp0[1];
  for (int it = 0; it < nIter; ++it) {
    int j1 = j + 8;
    bool val1 = j1 < end;
    float4 rec1 = val1 ? es[j1] : make_float4(0.f, 0.f, 0.f, 0.f);
    int s1 = __float_as_int(rec1.x);
    const float4* hp1 = (const float4*)(h_in + s1 * 8);
    float4 hA1 = hp1[0], hB1 = hp1[1];
    // compute current stage
    int t0 = __float_as_int(rec0.y);
    const float4* sp = (const float4*)(embT + t0 * 64 + o * 8);
    float4 sv0 = sp[0], sv1 = sp[1];
    v2f stv[4] = {(v2f){sv0.x, sv0.y}, (v2f){sv0.z, sv0.w},
                  (v2f){sv1.x, sv1.y}, (v2f){sv1.z, sv1.w}};
    v2f hv[4] = {(v2f){hA0.x, hA0.y}, (v2f){hA0.z, hA0.w},
                 (v2f){hB0.x, hB0.y}, (v2f){hB0.z, hB0.w}};
    v2f ef0 = (v2f){rec0.z, rec0.z}, ef1 = (v2f){rec0.w, rec0.w};
    v2f msg = {0.f, 0.f};
#pragma unroll
    for (int p = 0; p < 4; p++) {
      v2f hval = ef0 * rwh0[p] + ef1 * rwh1[p] + rbh[p];
      v2f gval = ef0 * rwg0[p] + ef1 * rwg1[p] + rbg[p];
      msg += hv[p] * VMAX0(stv[p] * hval + gval);
    }
    acc += val0 ? (msg.x + msg.y) : 0.f;
    rec0 = rec1; hA0 = hA1; hB0 = hB1; val0 = val1; j = j1;
  }
  acc += __shfl_xor(acc, 8);
  acc += __shfl_xor(acc, 16);
  acc += __shfl_xor(acc, 32);
  const float* hn = h_in + n * 8;
  v2f rtv = {0.f, 0.f};
#pragma unroll
  for (int p = 0; p < 4; p++)
    rtv += (v2f){hn[2 * p], hn[2 * p + 1]} * rroot[p];
  float deg = (float)(end - beg);
  float val = fmaxf(rbias + rtv.x + rtv.y + acc / fmaxf(deg, 1.f), 0.f);
  if (lane < 8) h_out[n * 8 + o] = val;
}

// ---------------- fused layer 4 (cin=8, cout=64) ----------------------------
// One node per wave, lane = output channel. Edge record + h row wave-uniform
// -> s_loads; emb via transposed layout: 2x dwordx4 per edge (was 8 scalar).
__global__ __launch_bounds__(256) void layer_l4(
    const int* __restrict__ off, const float4* __restrict__ es,
    const float* __restrict__ h_in, const float* __restrict__ embT,
    const float* __restrict__ wh, const float* __restrict__ bh,
    const float* __restrict__ wg, const float* __restrict__ bg,
    const float* __restrict__ root, const float* __restrict__ bias,
    float* __restrict__ h_out) {
  int lane = threadIdx.x & 63;
  v2f rwh0[4], rwh1[4], rbh[4], rwg0[4], rwg1[4], rbg[4], rroot[4];
#pragma unroll
  for (int p = 0; p < 4; p++) {
    int a = (2 * p) * 64 + lane, b = (2 * p + 1) * 64 + lane;
    rwh0[p] = (v2f){wh[a], wh[b]};
    rwh1[p] = (v2f){wh[512 + a], wh[512 + b]};
    rbh[p]  = (v2f){bh[a], bh[b]};
    rwg0[p] = (v2f){wg[a], wg[b]};
    rwg1[p] = (v2f){wg[512 + a], wg[512 + b]};
    rbg[p]  = (v2f){bg[a], bg[b]};
    rroot[p] = (v2f){root[a], root[b]};
  }
  float rbias = bias[lane];
  int n = __builtin_amdgcn_readfirstlane((int)(blockIdx.x * 4) + (int)(threadIdx.x >> 6));
  int beg = off[n], end = off[n + 1];
  float acc0 = 0.f, acc1 = 0.f;
  int e = beg;
  for (; e + 2 <= end; e += 2) {
    float4 r0 = es[e], r1 = es[e + 1];            // uniform -> s_loads
    int s0 = __float_as_int(r0.x), t0 = __float_as_int(r0.y);
    int s1 = __float_as_int(r1.x), t1 = __float_as_int(r1.y);
    const float4* hp0 = (const float4*)(h_in + s0 * 8);
    const float4* hp1 = (const float4*)(h_in + s1 * 8);
    float4 a0 = hp0[0], a1 = hp0[1];
    float4 b0 = hp1[0], b1 = hp1[1];
    const float4* ep0 = (const float4*)(embT + t0 * 512 + lane * 8);
    const float4* ep1 = (const float4*)(embT + t1 * 512 + lane * 8);
    float4 s00 = ep0[0], s01 = ep0[1];
    float4 s10 = ep1[0], s11 = ep1[1];
    v2f sv0[4] = {(v2f){s00.x, s00.y}, (v2f){s00.z, s00.w},
                  (v2f){s01.x, s01.y}, (v2f){s01.z, s01.w}};
    v2f sv1[4] = {(v2f){s10.x, s10.y}, (v2f){s10.z, s10.w},
                  (v2f){s11.x, s11.y}, (v2f){s11.z, s11.w}};
    v2f hva[4] = {(v2f){a0.x, a0.y}, (v2f){a0.z, a0.w},
                  (v2f){a1.x, a1.y}, (v2f){a1.z, a1.w}};
    v2f hvb[4] = {(v2f){b0.x, b0.y}, (v2f){b0.z, b0.w},
                  (v2f){b1.x, b1.y}, (v2f){b1.z, b1.w}};
    v2f e00 = (v2f){r0.z, r0.z}, e01 = (v2f){r0.w, r0.w};
    v2f e10 = (v2f){r1.z, r1.z}, e11 = (v2f){r1.w, r1.w};
    v2f m0 = {0.f, 0.f}, m1 = {0.f, 0.f};
#pragma unroll
    for (int p = 0; p < 4; p++) {
      v2f hv0 = e00 * rwh0[p] + e01 * rwh1[p] + rbh[p];
      v2f gv0 = e00 * rwg0[p] + e01 * rwg1[p] + rbg[p];
      m0 += hva[p] * VMAX0(sv0[p] * hv0 + gv0);
      v2f hv1 = e10 * rwh0[p] + e11 * rwh1[p] + rbh[p];
      v2f gv1 = e10 * rwg0[p] + e11 * rwg1[p] + rbg[p];
      m1 += hvb[p] * VMAX0(sv1[p] * hv1 + gv1);
    }
    acc0 += m0.x + m0.y;
    acc1 += m1.x + m1.y;
  }
  if (e < end) {
    float4 r0 = es[e];
    int s0 = __float_as_int(r0.x), t0 = __float_as_int(r0.y);
    const float4* hp0 = (const float4*)(h_in + s0 * 8);
    float4 a0 = hp0[0], a1 = hp0[1];
    const float4* ep0 = (const float4*)(embT + t0 * 512 + lane * 8);
    float4 s00 = ep0[0], s01 = ep0[1];
    v2f sv0[4] = {(v2f){s00.x, s00.y}, (v2f){s00.z, s00.w},
                  (v2f){s01.x, s01.y}, (v2f){s01.z, s01.w}};
    v2f hva[4] = {(v2f){a0.x, a0.y}, (v2f){a0.z, a0.w},
                  (v2f){a1.x, a1.y}, (v2f){a1.z, a1.w}};
    v2f e00 = (v2f){r0.z, r0.z}, e01 = (v2f){r0.w, r0.w};
    v2f m0 = {0.f, 0.f};
#pragma unroll
    for (int p = 0; p < 4; p++) {
      v2f hv0 = e00 * rwh0[p] + e01 * rwh1[p] + rbh[p];
      v2f gv0 = e00 * rwg0[p] + e01 * rwg1[p] + rbg[p];
      m0 += hva[p] * VMAX0(sv0[p] * hv0 + gv0);
    }
    acc0 += m0.x + m0.y;
  }
  float acc = acc0 + acc1;
  float deg = (float)(end - beg);
  const float* hn = h_in + n * 8;
  v2f rtv = {0.f, 0.f};
#pragma unroll
  for (int p = 0; p < 4; p++)
    rtv += (v2f){hn[2 * p], hn[2 * p + 1]} * rroot[p];
  h_out[n * 64 + lane] = fmaxf(rbias + rtv.x + rtv.y + acc / fmaxf(deg, 1.f), 0.f);
}

// ---------------- gated pooling, phase 1: 320 blocks ------------------------
__global__ __launch_bounds__(256) void pool1_kernel(
    const float* __restrict__ h4, const int* __restrict__ ct,
    float* __restrict__ pooled, float* __restrict__ pcnt) {
  __shared__ float ss[4][64];
  __shared__ float sc[4];
  int b = blockIdx.x / 20, c = blockIdx.x % 20;
  int base = b * (NN / NBATCH) + c * 64;
  int o = threadIdx.x & 63, sub = threadIdx.x >> 6;
  float sum = 0.f, cnt = 0.f;
  for (int j = sub; j < 64; j += 4) {
    int n = base + j;
    if (ct[n] == 1) { sum += h4[n * 64 + o]; cnt += 1.f; }
  }
  ss[sub][o] = sum;
  if (o == 0) sc[sub] = cnt;
  __syncthreads();
  if (threadIdx.x < 64) {
    float tot = ss[0][o] + ss[1][o] + ss[2][o] + ss[3][o];
    unsafeAtomicAdd(&pooled[b * 64 + o], tot);
    if (o == 0) unsafeAtomicAdd(&pcnt[b], sc[0] + sc[1] + sc[2] + sc[3]);
  }
}

// ---------------- pooling phase 2 + classifier + sigmoid (1 block) ----------
__global__ __launch_bounds__(1024) void pool2_kernel(
    const float* __restrict__ pooled, const float* __restrict__ pcnt,
    const float* __restrict__ clf_w, const float* __restrict__ clf_b,
    float* __restrict__ out) {
  int b = threadIdx.x >> 6, o = threadIdx.x & 63;
  float c = pcnt[b];
  float v = (pooled[b * 64 + o] / fmaxf(c, 1.f)) * clf_w[o];
#pragma unroll
  for (int d = 32; d; d >>= 1) v += __shfl_down(v, d);
  if (o == 0) out[b] = 1.f / (1.f + expf(-(v + clf_b[0])));
}

// ---------------------------------------------------------------------------
extern "C" void kernel_launch(void* const* d_in, const int* in_sizes, int n_in,
                              void* d_out, int out_size, void* d_ws, size_t ws_size,
                              hipStream_t stream) {
  (void)in_sizes; (void)n_in; (void)out_size; (void)ws_size;
  const float* x     = (const float*)d_in[0];
  const int*   eidx  = (const int*)d_in[1];
  const int*   src   = eidx;
  const int*   dst   = eidx + NE;
  const int*   etype = (const int*)d_in[2];
  const float* eattr = (const float*)d_in[3];
  const int*   ct    = (const int*)d_in[4];
  const float *emb[4], *wh[4], *bh[4], *wg[4], *bg[4], *root[4], *bias[4];
  for (int l = 0; l < 4; l++) {
    int b0 = 6 + 7 * l;
    emb[l]  = (const float*)d_in[b0 + 0];
    wh[l]   = (const float*)d_in[b0 + 1];
    bh[l]   = (const float*)d_in[b0 + 2];
    wg[l]   = (const float*)d_in[b0 + 3];
    bg[l]   = (const float*)d_in[b0 + 4];
    root[l] = (const float*)d_in[b0 + 5];
    bias[l] = (const float*)d_in[b0 + 6];
  }
  const float* clf_w = (const float*)d_in[34];
  const float* clf_b = (const float*)d_in[35];
  float* outp = (float*)d_out;

  // workspace layout (floats): ~12.0 MB (<= 12.5 MB proven in round 1)
  float* ws  = (float*)d_ws;
  int*    off    = (int*)ws;                      // NN+1 (pad 20484)
  float4* es     = (float4*)(ws + 20484);         // NE float4
  float*  hA     = ws + 20484 + 4 * NE;           // 8N
  float*  hB     = hA + 8 * NN;                   // 8N
  float*  h4     = hB + 8 * NN;                   // 64N
  float*  embT1  = h4 + 64 * NN;                  // 36*128
  float*  embT2  = embT1 + 36 * 128;              // 36*64
  float*  embT3  = embT2 + 36 * 64;               // 36*64
  float*  embT4  = embT3 + 36 * 64;               // 36*512
  float*  pooled = embT4 + 36 * 512;              // 16*64
  float*  pcnt   = pooled + 16 * 64;              // 16
  int*    cnt    = (int*)h4;                      // alias (dead until L4)
  int*    cur    = cnt + NN;                      // alias

  // ---- build CSR by dst + transpose emb tables ----
  hipMemsetAsync(cnt, 0, NN * sizeof(int), stream);
  hipMemsetAsync(pooled, 0, (16 * 64 + 16) * sizeof(float), stream);
  hist_kernel<<<NE / 256, 256, 0, stream>>>(dst, cnt);
  transpose_kernel<<<72, 256, 0, stream>>>(emb[0], emb[1], emb[2], emb[3],
                                           embT1, embT2, embT3, embT4);
  scan_kernel<<<1, 1024, 0, stream>>>(cnt, off, cur);
  scatter_kernel<<<NE / 256, 256, 0, stream>>>(src, dst, etype, eattr, cur, es);

  // ---- 4 fused layers ----
  layer_small16<<<NN / 4, 256, 0, stream>>>(off, es, x, embT1,
      wh[0], bh[0], wg[0], bg[0], root[0], bias[0], hA);
  layer_small8<<<NN / 4, 256, 0, stream>>>(off, es, hA, embT2,
      wh[1], bh[1], wg[1], bg[1], root[1], bias[1], hB);
  layer_small8<<<NN / 4, 256, 0, stream>>>(off, es, hB, embT3,
      wh[2], bh[2], wg[2], bg[2], root[2], bias[2], hA);
  layer_l4<<<NN / 4, 256, 0, stream>>>(off, es, hA, embT4,
      wh[3], bh[3], wg[3], bg[3], root[3], bias[3], h4);

  // ---- pooling + classifier + sigmoid ----
  pool1_kernel<<<320, 256, 0, stream>>>(h4, ct, pooled, pcnt);
  pool2_kernel<<<1, 1024, 0, stream>>>(pooled, pcnt, clf_w, clf_b, outp);
}